// Round 11
// baseline (309.767 us; speedup 1.0000x reference)
//
#include <hip/hip_runtime.h>

typedef _Float16 f16;
typedef _Float16 f16x2 __attribute__((ext_vector_type(2)));
typedef _Float16 f16x4 __attribute__((ext_vector_type(4)));
typedef _Float16 f16x8 __attribute__((ext_vector_type(8)));
typedef float f32x4 __attribute__((ext_vector_type(4)));
typedef unsigned int uint;

#define KM 0.1f   // DT * TAU_MEM_INV
#define KS 0.8f   // 1 - DT * TAU_SYN_INV
#define AS1 __attribute__((address_space(1)))
#define AS3 __attribute__((address_space(3)))
#define EPS_LO 2.44140625e-4f  // 2^-12

// ---------- E1: enc+LIF0 sim (float4) -> spike bitmask Z[b][f] + column flags ----------
__global__ void enc_flags(const float* __restrict__ img, uint* __restrict__ Z,
                          uint* __restrict__ flags) {
  int idx = blockIdx.x * 256 + threadIdx.x;
  if (idx >= 128 * 3000) return;
  int b = idx / 3000, f = (idx - b * 3000) << 2;
  float4 t4 = *(const float4*)&img[b * 12000 + f];
  float x[4] = {t4.x, t4.y, t4.z, t4.w};
  float ve[4] = {0.f, 0.f, 0.f, 0.f}, vl[4] = {0.f, 0.f, 0.f, 0.f}, il[4] = {0.f, 0.f, 0.f, 0.f};
  uint m[4] = {0u, 0u, 0u, 0u};
  for (int t = 0; t < 32; ++t) {
#pragma unroll
    for (int e = 0; e < 4; ++e) {
      ve[e] = ve[e] + KM * (x[e] - ve[e]);
      float z0 = (ve[e] > 1.0f) ? 1.f : 0.f;
      ve[e] -= z0 * ve[e];
      float vd = vl[e] + KM * (il[e] - vl[e]);
      float id = KS * il[e];
      float z1 = (vd > 1.0f) ? 1.f : 0.f;
      m[e] |= (vd > 1.0f) ? (1u << t) : 0u;
      vl[e] = (1.f - z1) * vd;
      il[e] = id + z0;
    }
  }
  *(uint4*)&Z[b * 12032 + f] = make_uint4(m[0], m[1], m[2], m[3]);
  uint mask = 0u;
#pragma unroll
  for (int e = 0; e < 4; ++e) mask |= (m[e] ? 1u : 0u) << ((f & 31) + e);
  int lane = threadIdx.x & 63;
#pragma unroll
  for (int s = 1; s < 8; s <<= 1) mask |= (uint)__shfl_xor((int)mask, s);
  if ((lane & 7) == 0 && mask) atomicOr(&flags[f >> 5], mask);
}

// ---------- E2: popcount scan -> sorted colidx, inverse map pos[f], meta={K', Kpc} ----------
__global__ void scan_cols(const uint* __restrict__ flags, int* __restrict__ colidx,
                          int* __restrict__ pos, int* __restrict__ meta) {
  __shared__ int cnt[512];
  int t = threadIdx.x;
  uint w = (t < 376) ? flags[t] : 0u;
  cnt[t] = __popc(w);
  __syncthreads();
  for (int off = 1; off < 512; off <<= 1) {
    int v = cnt[t];
    int u = (t >= off) ? cnt[t - off] : 0;
    __syncthreads();
    cnt[t] = v + u;
    __syncthreads();
  }
  int base = cnt[t] - __popc(w);  // exclusive prefix
  int rank = 0;
  for (int bit = 0; bit < 32; ++bit) {
    int f = t * 32 + bit;
    if (f < 12032) {
      int alive = (int)((w >> bit) & 1u);
      if (alive) colidx[base + rank] = f;
      pos[f] = alive ? (base + rank) : -1;
      rank += alive;
    }
  }
  if (t == 511) {
    int K = cnt[511];
    meta[0] = K;
    meta[1] = (K + 63) & ~63;
  }
}

// ---------- E3: compacted A'[4096][Kpc] from Z bitmasks; row = b*32 + t ----------
__global__ void spike_gather(const uint* __restrict__ Z, f16* __restrict__ A,
                             const int* __restrict__ colidx, const int* __restrict__ meta) {
  int K = meta[0], Kpc = meta[1];
  if (Kpc == 0) return;
  int jp = Kpc >> 1;
  int total = 128 * jp;
  for (int i = blockIdx.x * 256 + threadIdx.x; i < total; i += gridDim.x * 256) {
    int b = i / jp, j = (i - b * jp) << 1;
    uint m0 = (j < K) ? Z[b * 12032 + colidx[j]] : 0u;
    uint m1 = (j + 1 < K) ? Z[b * 12032 + colidx[j + 1]] : 0u;
    size_t rowbase = (size_t)b * 32 * Kpc + j;
    for (int t = 0; t < 32; ++t) {
      f16x2 s;
      s[0] = (f16)(float)((m0 >> t) & 1u);
      s[1] = (f16)(float)((m1 >> t) & 1u);
      *(f16x2*)&A[rowbase + (size_t)t * Kpc] = s;
    }
  }
}

// ---------- P0: coalesced-read + LDS-compact + coalesced-write layer-0 weight prep ----------
// Each block owns 8 padded rows. Per row: read W[o][*] float4-coalesced, scatter alive
// hi/lo into compact LDS via pos[], write both compact rows f16x8-coalesced. Pad = 0.
__global__ void prep_w0_pack(const float* __restrict__ W, f16* __restrict__ dst,
                             const int* __restrict__ pos, const int* __restrict__ meta) {
  int K = meta[0], Kpc = meta[1];
  if (Kpc == 0) return;
  __shared__ f16 hl[2][12032];  // 47 KiB compact hi|lo rows
  const int tid = threadIdx.x;
  // zero the [K, Kpc) pad once (scatter never touches it)
  for (int j = K + tid; j < Kpc; j += 256) { hl[0][j] = (f16)0.f; hl[1][j] = (f16)0.f; }
  __syncthreads();
  for (int rr = 0; rr < 8; ++rr) {
    int o = blockIdx.x * 8 + rr;
    if (o < 2000) {
      for (int f4 = tid * 4; f4 < 12000; f4 += 1024) {
        float4 t = *(const float4*)&W[(size_t)o * 12000 + f4];
        float w[4] = {t.x, t.y, t.z, t.w};
#pragma unroll
        for (int e = 0; e < 4; ++e) {
          int p = pos[f4 + e];
          if (p >= 0) {
            f16 h = (f16)w[e];
            float hf = (float)h;
            if (__builtin_fabsf(hf) < 6.103515625e-05f) { h = (f16)0.f; hf = 0.f; }
            hl[0][p] = h;
            hl[1][p] = (f16)((w[e] - hf) * 4096.0f);
          }
        }
      }
    } else {
      for (int j = tid; j < K; j += 256) { hl[0][j] = (f16)0.f; hl[1][j] = (f16)0.f; }
    }
    __syncthreads();
    int r2 = ((o >> 4) << 5) + (o & 15);  // hi row; +16 = lo row
    for (int j8 = tid * 8; j8 < Kpc; j8 += 2048) {
      *(f16x8*)&dst[(size_t)r2 * Kpc + j8] = *(f16x8*)&hl[0][j8];
      *(f16x8*)&dst[(size_t)(r2 + 16) * Kpc + j8] = *(f16x8*)&hl[1][j8];
    }
    __syncthreads();  // WAR: next row's scatter must not race this row's LDS reads
  }
}

// ---------- weight prep for layers 1..5 (all interleaved W2) ----------
struct PrepArgs {
  const float* W[5];
  f16* dst[5];
  int Nr[5], Kr[5], Kp[5], Npd[5];
  int boff[6];
};

__global__ void prep_w_all(PrepArgs a) {
  int blk = blockIdx.x;
  int k = 0;
#pragma unroll
  for (int j = 0; j < 4; ++j) k += (blk >= a.boff[j + 1]) ? 1 : 0;
  int i = (blk - a.boff[k]) * 256 + threadIdx.x;
  int Kp = a.Kp[k];
  int kp4 = Kp >> 2;
  int total4 = a.Npd[k] * kp4;
  if (i >= total4) return;
  int o = i / kp4, f = (i - o * kp4) << 2;
  float w[4] = {0.f, 0.f, 0.f, 0.f};
  if (o < a.Nr[k] && f < a.Kr[k]) {
    float4 t = *(const float4*)&a.W[k][(size_t)o * a.Kr[k] + f];
    w[0] = t.x; w[1] = t.y; w[2] = t.z; w[3] = t.w;
  }
  f16x4 h4, l4;
#pragma unroll
  for (int e = 0; e < 4; ++e) {
    f16 h = (f16)w[e];
    float hf = (float)h;
    if (__builtin_fabsf(hf) < 6.103515625e-05f) { h = (f16)0.f; hf = 0.f; }
    h4[e] = h;
    l4[e] = (f16)((w[e] - hf) * 4096.0f);
  }
  int r2 = ((o >> 4) << 5) + (o & 15);
  *(f16x4*)&a.dst[k][(size_t)r2 * Kp + f] = h4;
  *(f16x4*)&a.dst[k][(size_t)(r2 + 16) * Kp + f] = l4;
}

// ---------- fused GEMM + LI_k + LIF_{k+1}, templated on wave-rows ----------
// WM=4: BM=256, 512 thr (layer 0). WM=2: BM=128, 256 thr (layers 1..5).
// Rows ordered row = b*32 + t. Gout != nullptr (last layer): plain f32 C write.
// Else: epilogue runs exact li_lif fp32 recurrence via per-wave LDS scratch and
// writes next-layer spikes (f16, coalesced).
template <int WM>
__global__ __launch_bounds__(WM * 128, 4)
void gemm_fused(const f16* __restrict__ A, const f16* __restrict__ B2,
                f16* __restrict__ Spk, float* __restrict__ Gout,
                const int* __restrict__ kpcp, int KpFixed, int Np) {
  constexpr int BM = WM * 64;
  constexpr int NT = WM * 128;
  constexpr int BI = 1024 / NT;
  __shared__ f16 smem[BM * 64 + 128 * 64];
  f16* sA = smem;
  f16* sB = smem + BM * 64;
  const int Kp = kpcp ? kpcp[1] : KpFixed;
  const int tid = threadIdx.x;
  const int lane = tid & 63;
  const int wave = tid >> 6;
  const int wr = wave >> 1;
  const int wc = wave & 1;

  const int nx = gridDim.x;
  const int flat = blockIdx.y * nx + blockIdx.x;
  const int cpx = (nx * gridDim.y) >> 3;
  const int id = (flat & 7) * cpx + (flat >> 3);
  const int m0 = (id / nx) * BM;
  const int n0 = (id % nx) * 128;

  f32x4 zero = {0.f, 0.f, 0.f, 0.f};
  f32x4 acc[4][4];
#pragma unroll
  for (int m = 0; m < 4; ++m)
#pragma unroll
    for (int n = 0; n < 4; ++n) acc[m][n] = zero;

  const f16* Abase = A + (size_t)m0 * Kp;
  const f16* Bbase = B2 + (size_t)n0 * Kp;
  const int nkt = Kp >> 6;
  for (int kt = 0; kt < nkt; ++kt) {
    __syncthreads();
    const f16* Ab = Abase + (size_t)kt * 64;
    const f16* Bb = Bbase + (size_t)kt * 64;
#pragma unroll
    for (int j = 0; j < 4; ++j) {  // A: BM*8 chunks = 4*NT
      int q = j * NT + tid;
      int r = q >> 3, c = ((q & 7) ^ (r & 7)) * 8;
      __builtin_amdgcn_global_load_lds((const AS1 void*)(Ab + (size_t)r * Kp + c),
                                       (AS3 void*)(&sA[q * 8]), 16, 0, 0);
    }
#pragma unroll
    for (int j = 0; j < BI; ++j) {  // B: 1024 chunks
      int q = j * NT + tid;
      int r = q >> 3, c = ((q & 7) ^ (r & 7)) * 8;
      __builtin_amdgcn_global_load_lds((const AS1 void*)(Bb + (size_t)r * Kp + c),
                                       (AS3 void*)(&sB[q * 8]), 16, 0, 0);
    }
    __syncthreads();
#pragma unroll
    for (int kk = 0; kk < 2; ++kk) {
      const int lr = lane & 15;
      const int hq = lane >> 4;
      f16x8 af[4], bf[4];
#pragma unroll
      for (int m = 0; m < 4; ++m) {
        int R = wr * 64 + m * 16 + lr;
        int ch = (kk * 4 + hq) ^ (R & 7);
        af[m] = *(const f16x8*)&sA[R * 64 + ch * 8];
      }
#pragma unroll
      for (int n = 0; n < 4; ++n) {
        int R = wc * 64 + n * 16 + lr;
        int ch = (kk * 4 + hq) ^ (R & 7);
        bf[n] = *(const f16x8*)&sB[R * 64 + ch * 8];
      }
#pragma unroll
      for (int m = 0; m < 4; ++m)
#pragma unroll
        for (int n = 0; n < 4; ++n)
          acc[m][n] = __builtin_amdgcn_mfma_f32_16x16x32_f16(af[m], bf[n], acc[m][n], 0, 0, 0);
    }
  }

  const int lr = lane & 15, lq = lane >> 4;
  if (Gout) {  // last layer: plain f32 write (block-uniform branch)
#pragma unroll
    for (int m = 0; m < 4; ++m)
#pragma unroll
      for (int j = 0; j < 2; ++j) {
        int col = (n0 >> 1) + wc * 32 + j * 16 + lr;
#pragma unroll
        for (int i = 0; i < 4; ++i) {
          int row = m0 + wr * 64 + m * 16 + lq * 4 + i;
          Gout[(size_t)row * Np + col] = acc[m][2 * j][i] + EPS_LO * acc[m][2 * j + 1][i];
        }
      }
    return;
  }

  // ---- fused LI+LIF epilogue: per wave, 64 rows (= 2 batches x 32 t) x 32 cols ----
  __syncthreads();
  float* scr = (float*)smem + wave * 1152;  // [64][17] f32 per-wave scratch
  const int baseRow = m0 + wr * 64;
#pragma unroll
  for (int h = 0; h < 2; ++h) {
#pragma unroll
    for (int m = 0; m < 4; ++m)
#pragma unroll
      for (int i = 0; i < 4; ++i)
        scr[(m * 16 + lq * 4 + i) * 17 + lr] = acc[m][2 * h][i] + EPS_LO * acc[m][2 * h + 1][i];
    __syncthreads();
    if (lane < 32) {
      int bl = lane >> 4, c = lane & 15;
      float vL = 0.f, iL = 0.f, vF = 0.f, iF = 0.f;
      for (int t = 0; t < 32; ++t) {
        float g = scr[(bl * 32 + t) * 17 + c];
        float ij = iL + g;
        vL = vL + KM * (ij - vL);
        iL = KS * ij;
        float vd = vF + KM * (iF - vF);
        float idec = KS * iF;
        float z = (vd > 1.0f) ? 1.f : 0.f;
        vF = (1.f - z) * vd;
        iF = idec + vL;
        scr[(bl * 32 + t) * 17 + c] = z;
      }
    }
    __syncthreads();
    {
      int row = lane;
      f16x8 v0, v1;
#pragma unroll
      for (int cc = 0; cc < 8; ++cc) {
        v0[cc] = (f16)scr[row * 17 + cc];
        v1[cc] = (f16)scr[row * 17 + 8 + cc];
      }
      size_t go = (size_t)(baseRow + row) * Np + (n0 >> 1) + wc * 32 + h * 16;
      *(f16x8*)&Spk[go] = v0;
      *(f16x8*)&Spk[go + 8] = v1;
    }
    __syncthreads();
  }
}

// ---------- LI5 scan + max over t + log_softmax (rows = b*32+t) ----------
__global__ void final_k(const float* __restrict__ G, float* __restrict__ out) {
  int b = blockIdx.x;
  int n = threadIdx.x;
  float vL = 0.f, iL = 0.f, mx = -3.4e38f;
  for (int t = 0; t < 32; ++t) {
    float g = G[(size_t)(b * 32 + t) * 128 + n];
    float ij = iL + g;
    vL = vL + KM * (ij - vL);
    iL = KS * ij;
    mx = fmaxf(mx, vL);
  }
  float v = (n < 10) ? mx : -3.4e38f;
  float M = v;
#pragma unroll
  for (int s = 1; s < 16; s <<= 1) M = fmaxf(M, __shfl_xor(M, s));
  float e = (n < 10) ? expf(v - M) : 0.f;
  float sum = e;
#pragma unroll
  for (int s = 1; s < 16; s <<= 1) sum += __shfl_xor(sum, s);
  if (n < 10) out[b * 10 + n] = v - M - logf(sum);
}

extern "C" void kernel_launch(void* const* d_in, const int* in_sizes, int n_in,
                              void* d_out, int out_size, void* d_ws, size_t ws_size,
                              hipStream_t stream) {
  const float* img = (const float*)d_in[0];
  static const int Nr[6]  = {2000, 1500, 1000, 500, 100, 10};
  static const int Kr[6]  = {12000, 2000, 1500, 1000, 500, 100};
  static const int Npd[6] = {2048, 1536, 1024, 512, 128, 128};
  static const int Kpd[6] = {12032, 2048, 1536, 1024, 512, 128};

  char* p = (char*)d_ws;
  f16* wa[6];  // interleaved W2 [2*Npd][Kp] (layer 0: compacted K)
  wa[0] = (f16*)p; p += (size_t)4096 * 12032 * 2;  // max compacted size
  for (int k = 1; k < 6; ++k) {
    wa[k] = (f16*)p; p += (size_t)2 * Npd[k] * Kpd[k] * 2;
  }
  f16* Sbig = (f16*)p; p += (size_t)4096 * 12032 * 2;  // compacted L0 A
  f16* T0 = (f16*)p;   p += (size_t)4096 * 2048 * 2;   // spike ping
  f16* T1 = (f16*)p;   p += (size_t)4096 * 2048 * 2;   // spike pong
  float* G = (float*)p; p += (size_t)4096 * 128 * 4;   // L5 output only
  uint* Z = (uint*)p; p += (size_t)128 * 12032 * 4;    // spike bitmasks
  uint* flags = (uint*)p; p += 376 * 4;
  int* colidx = (int*)p; p += 12032 * 4;
  int* pos = (int*)p; p += 12032 * 4;
  int* meta = (int*)p; p += 2 * 4;

  // --- layer-0 column compaction chain ---
  hipMemsetAsync(flags, 0, 376 * 4, stream);
  enc_flags<<<(128 * 3000 + 255) / 256, 256, 0, stream>>>(img, Z, flags);
  scan_cols<<<1, 512, 0, stream>>>(flags, colidx, pos, meta);
  spike_gather<<<1024, 256, 0, stream>>>(Z, Sbig, colidx, meta);
  prep_w0_pack<<<256, 256, 0, stream>>>((const float*)d_in[1], wa[0], pos, meta);

  // --- layers 1..5 weight prep ---
  PrepArgs pa;
  int nb = 0;
  for (int k = 1; k < 6; ++k) {
    int kk = k - 1;
    pa.W[kk] = (const float*)d_in[k + 1];
    pa.dst[kk] = wa[k];
    pa.Nr[kk] = Nr[k]; pa.Kr[kk] = Kr[k]; pa.Kp[kk] = Kpd[k]; pa.Npd[kk] = Npd[k];
    pa.boff[kk] = nb;
    nb += ((Npd[k] * Kpd[k]) >> 2) / 256;
  }
  pa.boff[5] = nb;
  prep_w_all<<<nb, 256, 0, stream>>>(pa);

  // --- fused layer pipeline (spikes ping-pong T0/T1) ---
  const f16* Ain = Sbig;
  f16* T[2] = {T0, T1};
  for (int k = 0; k < 6; ++k) {
    f16* Sout = (k < 5) ? T[k & 1] : nullptr;
    float* Gout = (k == 5) ? G : nullptr;
    const int* kp = (k == 0) ? meta : nullptr;
    if (k < 1) {
      gemm_fused<4><<<dim3(2 * Npd[k] / 128, 16), dim3(512), 0, stream>>>(
          Ain, wa[k], Sout, Gout, kp, Kpd[k], Npd[k]);
    } else {
      gemm_fused<2><<<dim3(2 * Npd[k] / 128, 32), dim3(256), 0, stream>>>(
          Ain, wa[k], Sout, Gout, kp, Kpd[k], Npd[k]);
    }
    Ain = T[k & 1];
  }
  final_k<<<128, 64, 0, stream>>>(G, (float*)d_out);
}

// Round 12
// 260.262 us; speedup vs baseline: 1.1902x; 1.1902x over previous
//
#include <hip/hip_runtime.h>

typedef _Float16 f16;
typedef _Float16 f16x2 __attribute__((ext_vector_type(2)));
typedef _Float16 f16x4 __attribute__((ext_vector_type(4)));
typedef _Float16 f16x8 __attribute__((ext_vector_type(8)));
typedef float f32x4 __attribute__((ext_vector_type(4)));
typedef unsigned int uint;

#define KM 0.1f   // DT * TAU_MEM_INV
#define KS 0.8f   // 1 - DT * TAU_SYN_INV
#define AS1 __attribute__((address_space(1)))
#define AS3 __attribute__((address_space(3)))
#define EPS_LO 2.44140625e-4f  // 2^-12

// ---------- E1: enc+LIF0 sim (float4) -> spike bitmask Z[b][f] + column flags ----------
__global__ void enc_flags(const float* __restrict__ img, uint* __restrict__ Z,
                          uint* __restrict__ flags) {
  int idx = blockIdx.x * 256 + threadIdx.x;
  if (idx >= 128 * 3000) return;
  int b = idx / 3000, f = (idx - b * 3000) << 2;
  float4 t4 = *(const float4*)&img[b * 12000 + f];
  float x[4] = {t4.x, t4.y, t4.z, t4.w};
  float ve[4] = {0.f, 0.f, 0.f, 0.f}, vl[4] = {0.f, 0.f, 0.f, 0.f}, il[4] = {0.f, 0.f, 0.f, 0.f};
  uint m[4] = {0u, 0u, 0u, 0u};
  for (int t = 0; t < 32; ++t) {
#pragma unroll
    for (int e = 0; e < 4; ++e) {
      ve[e] = ve[e] + KM * (x[e] - ve[e]);
      float z0 = (ve[e] > 1.0f) ? 1.f : 0.f;
      ve[e] -= z0 * ve[e];
      float vd = vl[e] + KM * (il[e] - vl[e]);
      float id = KS * il[e];
      float z1 = (vd > 1.0f) ? 1.f : 0.f;
      m[e] |= (vd > 1.0f) ? (1u << t) : 0u;
      vl[e] = (1.f - z1) * vd;
      il[e] = id + z0;
    }
  }
  *(uint4*)&Z[b * 12032 + f] = make_uint4(m[0], m[1], m[2], m[3]);
  uint mask = 0u;
#pragma unroll
  for (int e = 0; e < 4; ++e) mask |= (m[e] ? 1u : 0u) << ((f & 31) + e);
  int lane = threadIdx.x & 63;
#pragma unroll
  for (int s = 1; s < 8; s <<= 1) mask |= (uint)__shfl_xor((int)mask, s);
  if ((lane & 7) == 0 && mask) atomicOr(&flags[f >> 5], mask);
}

// ---------- E2: popcount scan -> sorted colidx, meta={K', Kpc} ----------
__global__ void scan_cols(const uint* __restrict__ flags, int* __restrict__ colidx,
                          int* __restrict__ meta) {
  __shared__ int cnt[512];
  int t = threadIdx.x;
  uint w = (t < 376) ? flags[t] : 0u;
  cnt[t] = __popc(w);
  __syncthreads();
  for (int off = 1; off < 512; off <<= 1) {
    int v = cnt[t];
    int u = (t >= off) ? cnt[t - off] : 0;
    __syncthreads();
    cnt[t] = v + u;
    __syncthreads();
  }
  int base = cnt[t] - __popc(w);  // exclusive prefix
  uint ww = w;
  int r = 0;
  while (ww) {
    int p = __ffs(ww) - 1;
    colidx[base + r] = t * 32 + p;
    ww &= ww - 1;
    ++r;
  }
  if (t == 511) {
    int K = cnt[511];
    meta[0] = K;
    meta[1] = (K + 63) & ~63;
  }
}

// ---------- E3: compacted A'[4096][Kpc] from Z bitmasks; row = b*32 + t ----------
__global__ void spike_gather(const uint* __restrict__ Z, f16* __restrict__ A,
                             const int* __restrict__ colidx, const int* __restrict__ meta) {
  int K = meta[0], Kpc = meta[1];
  if (Kpc == 0) return;
  int jp = Kpc >> 1;
  int total = 128 * jp;
  for (int i = blockIdx.x * 256 + threadIdx.x; i < total; i += gridDim.x * 256) {
    int b = i / jp, j = (i - b * jp) << 1;
    uint m0 = (j < K) ? Z[b * 12032 + colidx[j]] : 0u;
    uint m1 = (j + 1 < K) ? Z[b * 12032 + colidx[j + 1]] : 0u;
    size_t rowbase = (size_t)b * 32 * Kpc + j;
    for (int t = 0; t < 32; ++t) {
      f16x2 s;
      s[0] = (f16)(float)((m0 >> t) & 1u);
      s[1] = (f16)(float)((m1 >> t) & 1u);
      *(f16x2*)&A[rowbase + (size_t)t * Kpc] = s;
    }
  }
}

// ---------- P0: one row per block: coalesced row-stage to LDS, LDS-gather, coalesced write ----------
// Reads W[o][*] float4-coalesced into 48KB LDS; thread j reads row[colidx[j]] (LDS),
// writes compact hi/lo rows coalesced. Pad columns (j>=K) written as 0.
__global__ __launch_bounds__(512) void prep_w0_row(const float* __restrict__ W,
                                                   f16* __restrict__ dst,
                                                   const int* __restrict__ colidx,
                                                   const int* __restrict__ meta) {
  __shared__ float row[12032];  // 48128 B -> 3 blocks/CU
  int K = meta[0], Kpc = meta[1];
  if (Kpc == 0) return;
  int o = blockIdx.x;  // 0..2047 (2000 real rows)
  int tid = threadIdx.x;
  bool live = (o < 2000);
  if (live) {
    for (int f4 = tid * 4; f4 < 12000; f4 += 2048)
      *(float4*)&row[f4] = *(const float4*)&W[(size_t)o * 12000 + f4];
  }
  __syncthreads();
  int r2 = ((o >> 4) << 5) + (o & 15);  // hi row; +16 = lo row
  f16* dh = dst + (size_t)r2 * Kpc;
  f16* dl = dst + (size_t)(r2 + 16) * Kpc;
  for (int j = tid; j < Kpc; j += 512) {
    float w = (live && j < K) ? row[colidx[j]] : 0.f;
    f16 h = (f16)w;
    float hf = (float)h;
    if (__builtin_fabsf(hf) < 6.103515625e-05f) { h = (f16)0.f; hf = 0.f; }
    dh[j] = h;
    dl[j] = (f16)((w - hf) * 4096.0f);
  }
}

// ---------- weight prep for layers 1..5 (all interleaved W2) ----------
struct PrepArgs {
  const float* W[5];
  f16* dst[5];
  int Nr[5], Kr[5], Kp[5], Npd[5];
  int boff[6];
};

__global__ void prep_w_all(PrepArgs a) {
  int blk = blockIdx.x;
  int k = 0;
#pragma unroll
  for (int j = 0; j < 4; ++j) k += (blk >= a.boff[j + 1]) ? 1 : 0;
  int i = (blk - a.boff[k]) * 256 + threadIdx.x;
  int Kp = a.Kp[k];
  int kp4 = Kp >> 2;
  int total4 = a.Npd[k] * kp4;
  if (i >= total4) return;
  int o = i / kp4, f = (i - o * kp4) << 2;
  float w[4] = {0.f, 0.f, 0.f, 0.f};
  if (o < a.Nr[k] && f < a.Kr[k]) {
    float4 t = *(const float4*)&a.W[k][(size_t)o * a.Kr[k] + f];
    w[0] = t.x; w[1] = t.y; w[2] = t.z; w[3] = t.w;
  }
  f16x4 h4, l4;
#pragma unroll
  for (int e = 0; e < 4; ++e) {
    f16 h = (f16)w[e];
    float hf = (float)h;
    if (__builtin_fabsf(hf) < 6.103515625e-05f) { h = (f16)0.f; hf = 0.f; }
    h4[e] = h;
    l4[e] = (f16)((w[e] - hf) * 4096.0f);
  }
  int r2 = ((o >> 4) << 5) + (o & 15);
  *(f16x4*)&a.dst[k][(size_t)r2 * Kp + f] = h4;
  *(f16x4*)&a.dst[k][(size_t)(r2 + 16) * Kp + f] = l4;
}

// ---------- fused GEMM + LI_k + LIF_{k+1}, templated on wave-rows ----------
// WM=4: BM=256, 512 thr (layers 0,1). WM=2: BM=128, 256 thr (layers 2..5).
// Rows ordered row = b*32 + t. Gout != nullptr (last layer): plain f32 C write.
// Else: epilogue runs exact li_lif fp32 recurrence via per-wave LDS scratch and
// writes next-layer spikes (f16, coalesced).
template <int WM>
__global__ __launch_bounds__(WM * 128, 4)
void gemm_fused(const f16* __restrict__ A, const f16* __restrict__ B2,
                f16* __restrict__ Spk, float* __restrict__ Gout,
                const int* __restrict__ kpcp, int KpFixed, int Np) {
  constexpr int BM = WM * 64;
  constexpr int NT = WM * 128;
  constexpr int BI = 1024 / NT;
  __shared__ f16 smem[BM * 64 + 128 * 64];
  f16* sA = smem;
  f16* sB = smem + BM * 64;
  const int Kp = kpcp ? kpcp[1] : KpFixed;
  const int tid = threadIdx.x;
  const int lane = tid & 63;
  const int wave = tid >> 6;
  const int wr = wave >> 1;
  const int wc = wave & 1;

  const int nx = gridDim.x;
  const int flat = blockIdx.y * nx + blockIdx.x;
  const int cpx = (nx * gridDim.y) >> 3;
  const int id = (flat & 7) * cpx + (flat >> 3);
  const int m0 = (id / nx) * BM;
  const int n0 = (id % nx) * 128;

  f32x4 zero = {0.f, 0.f, 0.f, 0.f};
  f32x4 acc[4][4];
#pragma unroll
  for (int m = 0; m < 4; ++m)
#pragma unroll
    for (int n = 0; n < 4; ++n) acc[m][n] = zero;

  const f16* Abase = A + (size_t)m0 * Kp;
  const f16* Bbase = B2 + (size_t)n0 * Kp;
  const int nkt = Kp >> 6;
  for (int kt = 0; kt < nkt; ++kt) {
    __syncthreads();
    const f16* Ab = Abase + (size_t)kt * 64;
    const f16* Bb = Bbase + (size_t)kt * 64;
#pragma unroll
    for (int j = 0; j < 4; ++j) {  // A: BM*8 chunks = 4*NT
      int q = j * NT + tid;
      int r = q >> 3, c = ((q & 7) ^ (r & 7)) * 8;
      __builtin_amdgcn_global_load_lds((const AS1 void*)(Ab + (size_t)r * Kp + c),
                                       (AS3 void*)(&sA[q * 8]), 16, 0, 0);
    }
#pragma unroll
    for (int j = 0; j < BI; ++j) {  // B: 1024 chunks
      int q = j * NT + tid;
      int r = q >> 3, c = ((q & 7) ^ (r & 7)) * 8;
      __builtin_amdgcn_global_load_lds((const AS1 void*)(Bb + (size_t)r * Kp + c),
                                       (AS3 void*)(&sB[q * 8]), 16, 0, 0);
    }
    __syncthreads();
#pragma unroll
    for (int kk = 0; kk < 2; ++kk) {
      const int lr = lane & 15;
      const int hq = lane >> 4;
      f16x8 af[4], bf[4];
#pragma unroll
      for (int m = 0; m < 4; ++m) {
        int R = wr * 64 + m * 16 + lr;
        int ch = (kk * 4 + hq) ^ (R & 7);
        af[m] = *(const f16x8*)&sA[R * 64 + ch * 8];
      }
#pragma unroll
      for (int n = 0; n < 4; ++n) {
        int R = wc * 64 + n * 16 + lr;
        int ch = (kk * 4 + hq) ^ (R & 7);
        bf[n] = *(const f16x8*)&sB[R * 64 + ch * 8];
      }
#pragma unroll
      for (int m = 0; m < 4; ++m)
#pragma unroll
        for (int n = 0; n < 4; ++n)
          acc[m][n] = __builtin_amdgcn_mfma_f32_16x16x32_f16(af[m], bf[n], acc[m][n], 0, 0, 0);
    }
  }

  const int lr = lane & 15, lq = lane >> 4;
  if (Gout) {  // last layer: plain f32 write (block-uniform branch)
#pragma unroll
    for (int m = 0; m < 4; ++m)
#pragma unroll
      for (int j = 0; j < 2; ++j) {
        int col = (n0 >> 1) + wc * 32 + j * 16 + lr;
#pragma unroll
        for (int i = 0; i < 4; ++i) {
          int row = m0 + wr * 64 + m * 16 + lq * 4 + i;
          Gout[(size_t)row * Np + col] = acc[m][2 * j][i] + EPS_LO * acc[m][2 * j + 1][i];
        }
      }
    return;
  }

  // ---- fused LI+LIF epilogue: per wave, 64 rows (= 2 batches x 32 t) x 32 cols ----
  __syncthreads();
  float* scr = (float*)smem + wave * 1152;  // [64][17] f32 per-wave scratch
  const int baseRow = m0 + wr * 64;
#pragma unroll
  for (int h = 0; h < 2; ++h) {
#pragma unroll
    for (int m = 0; m < 4; ++m)
#pragma unroll
      for (int i = 0; i < 4; ++i)
        scr[(m * 16 + lq * 4 + i) * 17 + lr] = acc[m][2 * h][i] + EPS_LO * acc[m][2 * h + 1][i];
    __syncthreads();
    if (lane < 32) {
      int bl = lane >> 4, c = lane & 15;
      float vL = 0.f, iL = 0.f, vF = 0.f, iF = 0.f;
      for (int t = 0; t < 32; ++t) {
        float g = scr[(bl * 32 + t) * 17 + c];
        float ij = iL + g;
        vL = vL + KM * (ij - vL);
        iL = KS * ij;
        float vd = vF + KM * (iF - vF);
        float idec = KS * iF;
        float z = (vd > 1.0f) ? 1.f : 0.f;
        vF = (1.f - z) * vd;
        iF = idec + vL;
        scr[(bl * 32 + t) * 17 + c] = z;
      }
    }
    __syncthreads();
    {
      int row = lane;
      f16x8 v0, v1;
#pragma unroll
      for (int cc = 0; cc < 8; ++cc) {
        v0[cc] = (f16)scr[row * 17 + cc];
        v1[cc] = (f16)scr[row * 17 + 8 + cc];
      }
      size_t go = (size_t)(baseRow + row) * Np + (n0 >> 1) + wc * 32 + h * 16;
      *(f16x8*)&Spk[go] = v0;
      *(f16x8*)&Spk[go + 8] = v1;
    }
    __syncthreads();
  }
}

// ---------- LI5 scan + max over t + log_softmax (rows = b*32+t) ----------
__global__ void final_k(const float* __restrict__ G, float* __restrict__ out) {
  int b = blockIdx.x;
  int n = threadIdx.x;
  float vL = 0.f, iL = 0.f, mx = -3.4e38f;
  for (int t = 0; t < 32; ++t) {
    float g = G[(size_t)(b * 32 + t) * 128 + n];
    float ij = iL + g;
    vL = vL + KM * (ij - vL);
    iL = KS * ij;
    mx = fmaxf(mx, vL);
  }
  float v = (n < 10) ? mx : -3.4e38f;
  float M = v;
#pragma unroll
  for (int s = 1; s < 16; s <<= 1) M = fmaxf(M, __shfl_xor(M, s));
  float e = (n < 10) ? expf(v - M) : 0.f;
  float sum = e;
#pragma unroll
  for (int s = 1; s < 16; s <<= 1) sum += __shfl_xor(sum, s);
  if (n < 10) out[b * 10 + n] = v - M - logf(sum);
}

extern "C" void kernel_launch(void* const* d_in, const int* in_sizes, int n_in,
                              void* d_out, int out_size, void* d_ws, size_t ws_size,
                              hipStream_t stream) {
  const float* img = (const float*)d_in[0];
  static const int Nr[6]  = {2000, 1500, 1000, 500, 100, 10};
  static const int Kr[6]  = {12000, 2000, 1500, 1000, 500, 100};
  static const int Npd[6] = {2048, 1536, 1024, 512, 128, 128};
  static const int Kpd[6] = {12032, 2048, 1536, 1024, 512, 128};

  char* p = (char*)d_ws;
  f16* wa[6];  // interleaved W2 [2*Npd][Kp] (layer 0: compacted K)
  wa[0] = (f16*)p; p += (size_t)4096 * 12032 * 2;  // max compacted size
  for (int k = 1; k < 6; ++k) {
    wa[k] = (f16*)p; p += (size_t)2 * Npd[k] * Kpd[k] * 2;
  }
  f16* Sbig = (f16*)p; p += (size_t)4096 * 12032 * 2;  // compacted L0 A
  f16* T0 = (f16*)p;   p += (size_t)4096 * 2048 * 2;   // spike ping
  f16* T1 = (f16*)p;   p += (size_t)4096 * 2048 * 2;   // spike pong
  float* G = (float*)p; p += (size_t)4096 * 128 * 4;   // L5 output only
  uint* Z = (uint*)p; p += (size_t)128 * 12032 * 4;    // spike bitmasks
  uint* flags = (uint*)p; p += 376 * 4;
  int* colidx = (int*)p; p += 12032 * 4;
  int* meta = (int*)p; p += 2 * 4;

  // --- layer-0 column compaction chain ---
  hipMemsetAsync(flags, 0, 376 * 4, stream);
  enc_flags<<<(128 * 3000 + 255) / 256, 256, 0, stream>>>(img, Z, flags);
  scan_cols<<<1, 512, 0, stream>>>(flags, colidx, meta);
  spike_gather<<<1024, 256, 0, stream>>>(Z, Sbig, colidx, meta);
  prep_w0_row<<<2048, 512, 0, stream>>>((const float*)d_in[1], wa[0], colidx, meta);

  // --- layers 1..5 weight prep ---
  PrepArgs pa;
  int nb = 0;
  for (int k = 1; k < 6; ++k) {
    int kk = k - 1;
    pa.W[kk] = (const float*)d_in[k + 1];
    pa.dst[kk] = wa[k];
    pa.Nr[kk] = Nr[k]; pa.Kr[kk] = Kr[k]; pa.Kp[kk] = Kpd[k]; pa.Npd[kk] = Npd[k];
    pa.boff[kk] = nb;
    nb += ((Npd[k] * Kpd[k]) >> 2) / 256;
  }
  pa.boff[5] = nb;
  prep_w_all<<<nb, 256, 0, stream>>>(pa);

  // --- fused layer pipeline (spikes ping-pong T0/T1) ---
  const f16* Ain = Sbig;
  f16* T[2] = {T0, T1};
  for (int k = 0; k < 6; ++k) {
    f16* Sout = (k < 5) ? T[k & 1] : nullptr;
    float* Gout = (k == 5) ? G : nullptr;
    const int* kp = (k == 0) ? meta : nullptr;
    if (k < 2) {
      gemm_fused<4><<<dim3(2 * Npd[k] / 128, 16), dim3(512), 0, stream>>>(
          Ain, wa[k], Sout, Gout, kp, Kpd[k], Npd[k]);
    } else {
      gemm_fused<2><<<dim3(2 * Npd[k] / 128, 32), dim3(256), 0, stream>>>(
          Ain, wa[k], Sout, Gout, kp, Kpd[k], Npd[k]);
    }
    Ain = T[k & 1];
  }
  final_k<<<128, 64, 0, stream>>>(G, (float*)d_out);
}

// Round 13
// 220.322 us; speedup vs baseline: 1.4060x; 1.1813x over previous
//
#include <hip/hip_runtime.h>

typedef _Float16 f16;
typedef _Float16 f16x2 __attribute__((ext_vector_type(2)));
typedef _Float16 f16x4 __attribute__((ext_vector_type(4)));
typedef _Float16 f16x8 __attribute__((ext_vector_type(8)));
typedef float f32x4 __attribute__((ext_vector_type(4)));
typedef unsigned int uint;

#define KM 0.1f   // DT * TAU_MEM_INV
#define KS 0.8f   // 1 - DT * TAU_SYN_INV
#define AS1 __attribute__((address_space(1)))
#define AS3 __attribute__((address_space(3)))
#define EPS_LO 2.44140625e-4f  // 2^-12

// ---------- E1: enc+LIF0 sim (float4) -> spike bitmask Z[b][f] + column flags ----------
__global__ void enc_flags(const float* __restrict__ img, uint* __restrict__ Z,
                          uint* __restrict__ flags) {
  int idx = blockIdx.x * 256 + threadIdx.x;
  if (idx >= 128 * 3000) return;
  int b = idx / 3000, f = (idx - b * 3000) << 2;
  float4 t4 = *(const float4*)&img[b * 12000 + f];
  float x[4] = {t4.x, t4.y, t4.z, t4.w};
  float ve[4] = {0.f, 0.f, 0.f, 0.f}, vl[4] = {0.f, 0.f, 0.f, 0.f}, il[4] = {0.f, 0.f, 0.f, 0.f};
  uint m[4] = {0u, 0u, 0u, 0u};
  for (int t = 0; t < 32; ++t) {
#pragma unroll
    for (int e = 0; e < 4; ++e) {
      ve[e] = ve[e] + KM * (x[e] - ve[e]);
      float z0 = (ve[e] > 1.0f) ? 1.f : 0.f;
      ve[e] -= z0 * ve[e];
      float vd = vl[e] + KM * (il[e] - vl[e]);
      float id = KS * il[e];
      float z1 = (vd > 1.0f) ? 1.f : 0.f;
      m[e] |= (vd > 1.0f) ? (1u << t) : 0u;
      vl[e] = (1.f - z1) * vd;
      il[e] = id + z0;
    }
  }
  *(uint4*)&Z[b * 12032 + f] = make_uint4(m[0], m[1], m[2], m[3]);
  uint mask = 0u;
#pragma unroll
  for (int e = 0; e < 4; ++e) mask |= (m[e] ? 1u : 0u) << ((f & 31) + e);
  int lane = threadIdx.x & 63;
#pragma unroll
  for (int s = 1; s < 8; s <<= 1) mask |= (uint)__shfl_xor((int)mask, s);
  if ((lane & 7) == 0 && mask) atomicOr(&flags[f >> 5], mask);
}

// ---------- E2: popcount scan -> sorted colidx, meta={K', Kpc}; word-count param ----------
__global__ void scan_cols(const uint* __restrict__ flags, int* __restrict__ colidx,
                          int* __restrict__ meta, int nwords) {
  __shared__ int cnt[512];
  int t = threadIdx.x;
  uint w = (t < nwords) ? flags[t] : 0u;
  cnt[t] = __popc(w);
  __syncthreads();
  for (int off = 1; off < 512; off <<= 1) {
    int v = cnt[t];
    int u = (t >= off) ? cnt[t - off] : 0;
    __syncthreads();
    cnt[t] = v + u;
    __syncthreads();
  }
  int base = cnt[t] - __popc(w);  // exclusive prefix
  uint ww = w;
  int r = 0;
  while (ww) {
    int p = __ffs(ww) - 1;
    colidx[base + r] = t * 32 + p;
    ww &= ww - 1;
    ++r;
  }
  if (t == 511) {
    int K = cnt[511];
    meta[0] = K;
    meta[1] = (K + 63) & ~63;
  }
}

// ---------- E3: compacted A'[4096][Kpc] from Z bitmasks; row = b*32 + t ----------
__global__ void spike_gather(const uint* __restrict__ Z, f16* __restrict__ A,
                             const int* __restrict__ colidx, const int* __restrict__ meta) {
  int K = meta[0], Kpc = meta[1];
  if (Kpc == 0) return;
  int jp = Kpc >> 1;
  int total = 128 * jp;
  for (int i = blockIdx.x * 256 + threadIdx.x; i < total; i += gridDim.x * 256) {
    int b = i / jp, j = (i - b * jp) << 1;
    uint m0 = (j < K) ? Z[b * 12032 + colidx[j]] : 0u;
    uint m1 = (j + 1 < K) ? Z[b * 12032 + colidx[j + 1]] : 0u;
    size_t rowbase = (size_t)b * 32 * Kpc + j;
    for (int t = 0; t < 32; ++t) {
      f16x2 s;
      s[0] = (f16)(float)((m0 >> t) & 1u);
      s[1] = (f16)(float)((m1 >> t) & 1u);
      *(f16x2*)&A[rowbase + (size_t)t * Kpc] = s;
    }
  }
}

// ---------- P0: one row per block: coalesced row-stage to LDS, LDS-gather, coalesced write ----------
__global__ __launch_bounds__(512) void prep_w0_row(const float* __restrict__ W,
                                                   f16* __restrict__ dst,
                                                   const int* __restrict__ colidx,
                                                   const int* __restrict__ meta) {
  __shared__ float row[12032];  // 48128 B -> 3 blocks/CU
  int K = meta[0], Kpc = meta[1];
  if (Kpc == 0) return;
  int o = blockIdx.x;  // 0..2047 (2000 real rows)
  int tid = threadIdx.x;
  bool live = (o < 2000);
  if (live) {
    for (int f4 = tid * 4; f4 < 12000; f4 += 2048)
      *(float4*)&row[f4] = *(const float4*)&W[(size_t)o * 12000 + f4];
  }
  __syncthreads();
  int r2 = ((o >> 4) << 5) + (o & 15);  // hi row; +16 = lo row
  f16* dh = dst + (size_t)r2 * Kpc;
  f16* dl = dst + (size_t)(r2 + 16) * Kpc;
  for (int j = tid; j < Kpc; j += 512) {
    float w = (live && j < K) ? row[colidx[j]] : 0.f;
    f16 h = (f16)w;
    float hf = (float)h;
    if (__builtin_fabsf(hf) < 6.103515625e-05f) { h = (f16)0.f; hf = 0.f; }
    dh[j] = h;
    dl[j] = (f16)((w - hf) * 4096.0f);
  }
}

// ---------- P1: layer-1 weight prep at runtime-compacted columns (clone of P0) ----------
__global__ __launch_bounds__(512) void prep_w1_row(const float* __restrict__ W,
                                                   f16* __restrict__ dst,
                                                   const int* __restrict__ colidx,
                                                   const int* __restrict__ meta) {
  __shared__ float row[2000];  // 8 KB
  int K = meta[0], Kpc = meta[1];
  if (Kpc == 0) return;
  int o = blockIdx.x;  // 0..1535 (1500 real rows)
  int tid = threadIdx.x;
  bool live = (o < 1500);
  if (live) {
    for (int f4 = tid * 4; f4 < 2000; f4 += 2048)
      *(float4*)&row[f4] = *(const float4*)&W[(size_t)o * 2000 + f4];
  }
  __syncthreads();
  int r2 = ((o >> 4) << 5) + (o & 15);
  f16* dh = dst + (size_t)r2 * Kpc;
  f16* dl = dst + (size_t)(r2 + 16) * Kpc;
  for (int j = tid; j < Kpc; j += 512) {
    float w = (live && j < K) ? row[colidx[j]] : 0.f;
    f16 h = (f16)w;
    float hf = (float)h;
    if (__builtin_fabsf(hf) < 6.103515625e-05f) { h = (f16)0.f; hf = 0.f; }
    dh[j] = h;
    dl[j] = (f16)((w - hf) * 4096.0f);
  }
}

// ---------- compact dense spike matrix columns: dst[row][j] = src[row][colidx[j]] ----------
__global__ void gather_cols(const f16* __restrict__ src, f16* __restrict__ dst,
                            const int* __restrict__ colidx, const int* __restrict__ meta,
                            int srcW) {
  int K = meta[0], Kpc = meta[1];
  if (Kpc == 0) return;
  int row = blockIdx.x;  // 4096
  const f16* s = src + (size_t)row * srcW;
  f16* d = dst + (size_t)row * Kpc;
  for (int j = threadIdx.x; j < Kpc; j += 256)
    d[j] = (j < K) ? s[colidx[j]] : (f16)0.f;
}

// ---------- weight prep for layers 2..5 (all interleaved W2) ----------
struct PrepArgs {
  const float* W[5];
  f16* dst[5];
  int Nr[5], Kr[5], Kp[5], Npd[5];
  int boff[6];
};

__global__ void prep_w_all(PrepArgs a) {
  int blk = blockIdx.x;
  int k = 0;
#pragma unroll
  for (int j = 0; j < 4; ++j) k += (blk >= a.boff[j + 1]) ? 1 : 0;
  int i = (blk - a.boff[k]) * 256 + threadIdx.x;
  int Kp = a.Kp[k];
  int kp4 = Kp >> 2;
  int total4 = a.Npd[k] * kp4;
  if (i >= total4) return;
  int o = i / kp4, f = (i - o * kp4) << 2;
  float w[4] = {0.f, 0.f, 0.f, 0.f};
  if (o < a.Nr[k] && f < a.Kr[k]) {
    float4 t = *(const float4*)&a.W[k][(size_t)o * a.Kr[k] + f];
    w[0] = t.x; w[1] = t.y; w[2] = t.z; w[3] = t.w;
  }
  f16x4 h4, l4;
#pragma unroll
  for (int e = 0; e < 4; ++e) {
    f16 h = (f16)w[e];
    float hf = (float)h;
    if (__builtin_fabsf(hf) < 6.103515625e-05f) { h = (f16)0.f; hf = 0.f; }
    h4[e] = h;
    l4[e] = (f16)((w[e] - hf) * 4096.0f);
  }
  int r2 = ((o >> 4) << 5) + (o & 15);
  *(f16x4*)&a.dst[k][(size_t)r2 * Kp + f] = h4;
  *(f16x4*)&a.dst[k][(size_t)(r2 + 16) * Kp + f] = l4;
}

// ---------- fused GEMM + LI_k + LIF_{k+1}, templated on wave-rows ----------
// WM=4: BM=256, 512 thr. WM=2: BM=128, 256 thr. Rows ordered row = b*32 + t.
// Gout != nullptr: plain f32 C write (last layer). Else: epilogue runs exact li_lif
// fp32 recurrence via per-wave LDS scratch, writes next-layer spikes (f16), and if
// colFlags != nullptr also ORs per-column spike-aliveness (1 ballot-atomic per wave/h).
template <int WM>
__global__ __launch_bounds__(WM * 128, 4)
void gemm_fused(const f16* __restrict__ A, const f16* __restrict__ B2,
                f16* __restrict__ Spk, float* __restrict__ Gout,
                const int* __restrict__ kpcp, int KpFixed, int Np,
                uint* __restrict__ colFlags) {
  constexpr int BM = WM * 64;
  constexpr int NT = WM * 128;
  constexpr int BI = 1024 / NT;
  __shared__ f16 smem[BM * 64 + 128 * 64];
  f16* sA = smem;
  f16* sB = smem + BM * 64;
  const int Kp = kpcp ? kpcp[1] : KpFixed;
  const int tid = threadIdx.x;
  const int lane = tid & 63;
  const int wave = tid >> 6;
  const int wr = wave >> 1;
  const int wc = wave & 1;

  const int nx = gridDim.x;
  const int flat = blockIdx.y * nx + blockIdx.x;
  const int cpx = (nx * gridDim.y) >> 3;
  const int id = (flat & 7) * cpx + (flat >> 3);
  const int m0 = (id / nx) * BM;
  const int n0 = (id % nx) * 128;

  f32x4 zero = {0.f, 0.f, 0.f, 0.f};
  f32x4 acc[4][4];
#pragma unroll
  for (int m = 0; m < 4; ++m)
#pragma unroll
    for (int n = 0; n < 4; ++n) acc[m][n] = zero;

  const f16* Abase = A + (size_t)m0 * Kp;
  const f16* Bbase = B2 + (size_t)n0 * Kp;
  const int nkt = Kp >> 6;
  for (int kt = 0; kt < nkt; ++kt) {
    __syncthreads();
    const f16* Ab = Abase + (size_t)kt * 64;
    const f16* Bb = Bbase + (size_t)kt * 64;
#pragma unroll
    for (int j = 0; j < 4; ++j) {  // A: BM*8 chunks = 4*NT
      int q = j * NT + tid;
      int r = q >> 3, c = ((q & 7) ^ (r & 7)) * 8;
      __builtin_amdgcn_global_load_lds((const AS1 void*)(Ab + (size_t)r * Kp + c),
                                       (AS3 void*)(&sA[q * 8]), 16, 0, 0);
    }
#pragma unroll
    for (int j = 0; j < BI; ++j) {  // B: 1024 chunks
      int q = j * NT + tid;
      int r = q >> 3, c = ((q & 7) ^ (r & 7)) * 8;
      __builtin_amdgcn_global_load_lds((const AS1 void*)(Bb + (size_t)r * Kp + c),
                                       (AS3 void*)(&sB[q * 8]), 16, 0, 0);
    }
    __syncthreads();
#pragma unroll
    for (int kk = 0; kk < 2; ++kk) {
      const int lr = lane & 15;
      const int hq = lane >> 4;
      f16x8 af[4], bf[4];
#pragma unroll
      for (int m = 0; m < 4; ++m) {
        int R = wr * 64 + m * 16 + lr;
        int ch = (kk * 4 + hq) ^ (R & 7);
        af[m] = *(const f16x8*)&sA[R * 64 + ch * 8];
      }
#pragma unroll
      for (int n = 0; n < 4; ++n) {
        int R = wc * 64 + n * 16 + lr;
        int ch = (kk * 4 + hq) ^ (R & 7);
        bf[n] = *(const f16x8*)&sB[R * 64 + ch * 8];
      }
#pragma unroll
      for (int m = 0; m < 4; ++m)
#pragma unroll
        for (int n = 0; n < 4; ++n)
          acc[m][n] = __builtin_amdgcn_mfma_f32_16x16x32_f16(af[m], bf[n], acc[m][n], 0, 0, 0);
    }
  }

  const int lr = lane & 15, lq = lane >> 4;
  if (Gout) {  // last layer: plain f32 write (block-uniform branch)
#pragma unroll
    for (int m = 0; m < 4; ++m)
#pragma unroll
      for (int j = 0; j < 2; ++j) {
        int col = (n0 >> 1) + wc * 32 + j * 16 + lr;
#pragma unroll
        for (int i = 0; i < 4; ++i) {
          int row = m0 + wr * 64 + m * 16 + lq * 4 + i;
          Gout[(size_t)row * Np + col] = acc[m][2 * j][i] + EPS_LO * acc[m][2 * j + 1][i];
        }
      }
    return;
  }

  // ---- fused LI+LIF epilogue: per wave, 64 rows (= 2 batches x 32 t) x 32 cols ----
  __syncthreads();
  float* scr = (float*)smem + wave * 1152;  // [64][17] f32 per-wave scratch
  const int baseRow = m0 + wr * 64;
#pragma unroll
  for (int h = 0; h < 2; ++h) {
#pragma unroll
    for (int m = 0; m < 4; ++m)
#pragma unroll
      for (int i = 0; i < 4; ++i)
        scr[(m * 16 + lq * 4 + i) * 17 + lr] = acc[m][2 * h][i] + EPS_LO * acc[m][2 * h + 1][i];
    __syncthreads();
    if (lane < 32) {
      int bl = lane >> 4, c = lane & 15;
      float vL = 0.f, iL = 0.f, vF = 0.f, iF = 0.f;
      for (int t = 0; t < 32; ++t) {
        float g = scr[(bl * 32 + t) * 17 + c];
        float ij = iL + g;
        vL = vL + KM * (ij - vL);
        iL = KS * ij;
        float vd = vF + KM * (iF - vF);
        float idec = KS * iF;
        float z = (vd > 1.0f) ? 1.f : 0.f;
        vF = (1.f - z) * vd;
        iF = idec + vL;
        scr[(bl * 32 + t) * 17 + c] = z;
      }
    }
    __syncthreads();
    {
      int row = lane;
      f16x8 v0, v1;
#pragma unroll
      for (int cc = 0; cc < 8; ++cc) {
        v0[cc] = (f16)scr[row * 17 + cc];
        v1[cc] = (f16)scr[row * 17 + 8 + cc];
      }
      size_t go = (size_t)(baseRow + row) * Np + (n0 >> 1) + wc * 32 + h * 16;
      *(f16x8*)&Spk[go] = v0;
      *(f16x8*)&Spk[go + 8] = v1;
      if (colFlags) {  // column spike-aliveness for next-layer K compaction
        uint bits = 0u;
#pragma unroll
        for (int cc = 0; cc < 8; ++cc) {
          bits |= (__any((float)v0[cc] != 0.f) ? 1u : 0u) << cc;
          bits |= (__any((float)v1[cc] != 0.f) ? 1u : 0u) << (8 + cc);
        }
        int cstart = (n0 >> 1) + wc * 32 + h * 16;  // multiple of 16
        if (lane == 0 && bits) atomicOr(&colFlags[cstart >> 5], bits << (cstart & 31));
      }
    }
    __syncthreads();
  }
}

// ---------- LI5 scan + max over t + log_softmax (rows = b*32+t) ----------
__global__ void final_k(const float* __restrict__ G, float* __restrict__ out) {
  int b = blockIdx.x;
  int n = threadIdx.x;
  float vL = 0.f, iL = 0.f, mx = -3.4e38f;
  for (int t = 0; t < 32; ++t) {
    float g = G[(size_t)(b * 32 + t) * 128 + n];
    float ij = iL + g;
    vL = vL + KM * (ij - vL);
    iL = KS * ij;
    mx = fmaxf(mx, vL);
  }
  float v = (n < 10) ? mx : -3.4e38f;
  float M = v;
#pragma unroll
  for (int s = 1; s < 16; s <<= 1) M = fmaxf(M, __shfl_xor(M, s));
  float e = (n < 10) ? expf(v - M) : 0.f;
  float sum = e;
#pragma unroll
  for (int s = 1; s < 16; s <<= 1) sum += __shfl_xor(sum, s);
  if (n < 10) out[b * 10 + n] = v - M - logf(sum);
}

extern "C" void kernel_launch(void* const* d_in, const int* in_sizes, int n_in,
                              void* d_out, int out_size, void* d_ws, size_t ws_size,
                              hipStream_t stream) {
  const float* img = (const float*)d_in[0];
  static const int Nr[6]  = {2000, 1500, 1000, 500, 100, 10};
  static const int Kr[6]  = {12000, 2000, 1500, 1000, 500, 100};
  static const int Npd[6] = {2048, 1536, 1024, 512, 128, 128};
  static const int Kpd[6] = {12032, 2048, 1536, 1024, 512, 128};

  char* p = (char*)d_ws;
  f16* wa[6];  // interleaved W2 [2*Npd][Kp] (layers 0,1: runtime-compacted K)
  wa[0] = (f16*)p; p += (size_t)4096 * 12032 * 2;  // max compacted size
  for (int k = 1; k < 6; ++k) {
    wa[k] = (f16*)p; p += (size_t)2 * Npd[k] * Kpd[k] * 2;
  }
  f16* Sbig = (f16*)p; p += (size_t)4096 * 12032 * 2;  // compacted L0 A
  f16* T0 = (f16*)p;   p += (size_t)4096 * 2048 * 2;   // spike ping
  f16* T1 = (f16*)p;   p += (size_t)4096 * 2048 * 2;   // spike pong
  float* G = (float*)p; p += (size_t)4096 * 128 * 4;   // L5 output only
  uint* Z = (uint*)p; p += (size_t)128 * 12032 * 4;    // spike bitmasks
  uint* flags = (uint*)p; p += 376 * 4;                // L0-input column flags
  uint* flags1 = (uint*)p; p += 64 * 4;                // L1-input column flags
  int* colidx = (int*)p; p += 12032 * 4;
  int* colidx1 = (int*)p; p += 2048 * 4;
  int* meta = (int*)p; p += 2 * 4;
  int* meta1 = (int*)p; p += 2 * 4;

  // --- layer-0 column compaction chain ---
  hipMemsetAsync(flags, 0, (376 + 64) * 4, stream);  // flags + flags1 (adjacent)
  enc_flags<<<(128 * 3000 + 255) / 256, 256, 0, stream>>>(img, Z, flags);
  scan_cols<<<1, 512, 0, stream>>>(flags, colidx, meta, 376);
  spike_gather<<<1024, 256, 0, stream>>>(Z, Sbig, colidx, meta);
  prep_w0_row<<<2048, 512, 0, stream>>>((const float*)d_in[1], wa[0], colidx, meta);

  // --- layers 2..5 weight prep (W1 prepped after L0, at compacted columns) ---
  PrepArgs pa;
  int nb = 0;
  for (int k = 2; k < 6; ++k) {
    int kk = k - 2;
    pa.W[kk] = (const float*)d_in[k + 1];
    pa.dst[kk] = wa[k];
    pa.Nr[kk] = Nr[k]; pa.Kr[kk] = Kr[k]; pa.Kp[kk] = Kpd[k]; pa.Npd[kk] = Npd[k];
    pa.boff[kk] = nb;
    nb += ((Npd[k] * Kpd[k]) >> 2) / 256;
  }
  pa.boff[4] = nb;
  pa.boff[5] = nb;
  prep_w_all<<<nb, 256, 0, stream>>>(pa);

  // --- L0: GEMM + LI0/LIF1 epilogue + column-aliveness flags ---
  gemm_fused<4><<<dim3(32, 16), dim3(512), 0, stream>>>(
      Sbig, wa[0], T0, nullptr, meta, 0, Npd[0], flags1);

  // --- L1 K-compaction: scan -> gather spikes -> prep W1 at alive columns ---
  scan_cols<<<1, 512, 0, stream>>>(flags1, colidx1, meta1, 64);
  gather_cols<<<4096, 256, 0, stream>>>(T0, T1, colidx1, meta1, Npd[0]);
  prep_w1_row<<<1536, 512, 0, stream>>>((const float*)d_in[2], wa[1], colidx1, meta1);

  // --- L1 (runtime K) then L2..L5; spikes alternate T0/T1 ---
  gemm_fused<4><<<dim3(2 * Npd[1] / 128, 16), dim3(512), 0, stream>>>(
      T1, wa[1], T0, nullptr, meta1, 0, Npd[1], nullptr);
  gemm_fused<2><<<dim3(2 * Npd[2] / 128, 32), dim3(256), 0, stream>>>(
      T0, wa[2], T1, nullptr, nullptr, Kpd[2], Npd[2], nullptr);
  gemm_fused<2><<<dim3(2 * Npd[3] / 128, 32), dim3(256), 0, stream>>>(
      T1, wa[3], T0, nullptr, nullptr, Kpd[3], Npd[3], nullptr);
  gemm_fused<2><<<dim3(2 * Npd[4] / 128, 32), dim3(256), 0, stream>>>(
      T0, wa[4], T1, nullptr, nullptr, Kpd[4], Npd[4], nullptr);
  gemm_fused<2><<<dim3(2 * Npd[5] / 128, 32), dim3(256), 0, stream>>>(
      T1, wa[5], nullptr, G, nullptr, Kpd[5], Npd[5], nullptr);
  final_k<<<128, 64, 0, stream>>>(G, (float*)d_out);
}

// Round 14
// 172.313 us; speedup vs baseline: 1.7977x; 1.2786x over previous
//
#include <hip/hip_runtime.h>

typedef _Float16 f16;
typedef _Float16 f16x2 __attribute__((ext_vector_type(2)));
typedef _Float16 f16x4 __attribute__((ext_vector_type(4)));
typedef _Float16 f16x8 __attribute__((ext_vector_type(8)));
typedef float f32x4 __attribute__((ext_vector_type(4)));
typedef unsigned int uint;

#define KM 0.1f   // DT * TAU_MEM_INV
#define KS 0.8f   // 1 - DT * TAU_SYN_INV
#define AS1 __attribute__((address_space(1)))
#define AS3 __attribute__((address_space(3)))
#define EPS_LO 2.44140625e-4f  // 2^-12
#define KCAP0 2560                       // per-group compacted-K cap (exp ~385)
#define ASTR ((size_t)512 * KCAP0)       // per-group A stride (f16 elems)
#define BSTR ((size_t)4096 * KCAP0)      // per-group W0 stride (f16 elems)

// ---------- E1: enc+LIF0 sim (float4) -> spike bitmask Z[b][f] + per-group column flags ----------
__global__ void enc_flags(const float* __restrict__ img, uint* __restrict__ Z,
                          uint* __restrict__ flags) {
  int idx = blockIdx.x * 256 + threadIdx.x;
  if (idx >= 128 * 3000) return;
  int b = idx / 3000, f = (idx - b * 3000) << 2;
  float4 t4 = *(const float4*)&img[b * 12000 + f];
  float x[4] = {t4.x, t4.y, t4.z, t4.w};
  float ve[4] = {0.f, 0.f, 0.f, 0.f}, vl[4] = {0.f, 0.f, 0.f, 0.f}, il[4] = {0.f, 0.f, 0.f, 0.f};
  uint m[4] = {0u, 0u, 0u, 0u};
  for (int t = 0; t < 32; ++t) {
#pragma unroll
    for (int e = 0; e < 4; ++e) {
      ve[e] = ve[e] + KM * (x[e] - ve[e]);
      float z0 = (ve[e] > 1.0f) ? 1.f : 0.f;
      ve[e] -= z0 * ve[e];
      float vd = vl[e] + KM * (il[e] - vl[e]);
      float id = KS * il[e];
      float z1 = (vd > 1.0f) ? 1.f : 0.f;
      m[e] |= (vd > 1.0f) ? (1u << t) : 0u;
      vl[e] = (1.f - z1) * vd;
      il[e] = id + z0;
    }
  }
  *(uint4*)&Z[b * 12032 + f] = make_uint4(m[0], m[1], m[2], m[3]);
  uint mask = 0u;
#pragma unroll
  for (int e = 0; e < 4; ++e) mask |= (m[e] ? 1u : 0u) << ((f & 31) + e);
  // 8-lane shuffle-OR pre-reduce: lanes 0..7 share b (3000 % 8 == 0) hence group g
  int lane = threadIdx.x & 63;
#pragma unroll
  for (int s = 1; s < 8; s <<= 1) mask |= (uint)__shfl_xor((int)mask, s);
  int g = b >> 4;
  if ((lane & 7) == 0 && mask) atomicOr(&flags[g * 376 + (f >> 5)], mask);
}

// ---------- E2: per-group popcount scan -> sorted colidx_g, meta_g={K, Kpc} ----------
__global__ void scan_cols(const uint* __restrict__ flagsIn, int* __restrict__ colidxOut,
                          int* __restrict__ metaOut, int nwords, int cstride, int cap) {
  __shared__ int cnt[512];
  int g = blockIdx.x;
  const uint* flags = flagsIn + g * nwords;
  int* colidx = colidxOut + g * cstride;
  int* meta = metaOut + g * 2;
  int t = threadIdx.x;
  uint w = (t < nwords) ? flags[t] : 0u;
  cnt[t] = __popc(w);
  __syncthreads();
  for (int off = 1; off < 512; off <<= 1) {
    int v = cnt[t];
    int u = (t >= off) ? cnt[t - off] : 0;
    __syncthreads();
    cnt[t] = v + u;
    __syncthreads();
  }
  int base = cnt[t] - __popc(w);  // exclusive prefix
  uint ww = w;
  int r = 0;
  while (ww) {
    int p = __ffs(ww) - 1;
    colidx[base + r] = t * 32 + p;
    ww &= ww - 1;
    ++r;
  }
  if (t == 511) {
    int K = cnt[511];
    if (K > cap) K = cap;  // safety clamp (6.6x expected margin)
    meta[0] = K;
    meta[1] = (K + 63) & ~63;
  }
}

// ---------- E3: per-group compacted A_g[512][Kpc_g] from Z bitmasks; row = b_local*32 + t ----------
__global__ void spike_gather(const uint* __restrict__ Z, f16* __restrict__ A,
                             const int* __restrict__ colidx, const int* __restrict__ meta) {
  int g = blockIdx.y;
  int K = meta[g * 2], Kpc = meta[g * 2 + 1];
  if (Kpc == 0) return;
  const int* cidx = colidx + g * 12032;
  int jp = Kpc >> 1;
  int total = 16 * jp;
  for (int i = blockIdx.x * 256 + threadIdx.x; i < total; i += gridDim.x * 256) {
    int bl = i / jp, j = (i - bl * jp) << 1;
    int b = g * 16 + bl;
    uint m0 = (j < K) ? Z[b * 12032 + cidx[j]] : 0u;
    uint m1 = (j + 1 < K) ? Z[b * 12032 + cidx[j + 1]] : 0u;
    size_t base = g * ASTR + (size_t)(bl * 32) * Kpc + j;
    for (int t = 0; t < 32; ++t) {
      f16x2 s;
      s[0] = (f16)(float)((m0 >> t) & 1u);
      s[1] = (f16)(float)((m1 >> t) & 1u);
      *(f16x2*)&A[base + (size_t)t * Kpc] = s;
    }
  }
}

// ---------- P0: per weight-row block: stage row to LDS once, emit 8 per-group compact hi/lo rows ----------
__global__ __launch_bounds__(512) void prep_w0_row(const float* __restrict__ W,
                                                   f16* __restrict__ dst,
                                                   const int* __restrict__ colidx,
                                                   const int* __restrict__ meta) {
  __shared__ float row[12032];  // 48128 B -> 3 blocks/CU
  int o = blockIdx.x;  // 0..2047 (2000 real rows)
  int tid = threadIdx.x;
  bool live = (o < 2000);
  if (live) {
    for (int f4 = tid * 4; f4 < 12000; f4 += 2048)
      *(float4*)&row[f4] = *(const float4*)&W[(size_t)o * 12000 + f4];
  }
  __syncthreads();
  int r2 = ((o >> 4) << 5) + (o & 15);  // hi row; +16 = lo row
  for (int g = 0; g < 8; ++g) {
    int K = meta[g * 2], Kpc = meta[g * 2 + 1];
    const int* cidx = colidx + g * 12032;
    f16* dh = dst + g * BSTR + (size_t)r2 * Kpc;
    f16* dl = dst + g * BSTR + (size_t)(r2 + 16) * Kpc;
    for (int j = tid; j < Kpc; j += 512) {
      float w = (live && j < K) ? row[cidx[j]] : 0.f;
      f16 h = (f16)w;
      float hf = (float)h;
      if (__builtin_fabsf(hf) < 6.103515625e-05f) { h = (f16)0.f; hf = 0.f; }
      dh[j] = h;
      dl[j] = (f16)((w - hf) * 4096.0f);
    }
  }
}

// ---------- P1: layer-1 weight prep at runtime-compacted columns ----------
__global__ __launch_bounds__(512) void prep_w1_row(const float* __restrict__ W,
                                                   f16* __restrict__ dst,
                                                   const int* __restrict__ colidx,
                                                   const int* __restrict__ meta) {
  __shared__ float row[2000];  // 8 KB
  int K = meta[0], Kpc = meta[1];
  if (Kpc == 0) return;
  int o = blockIdx.x;  // 0..1535 (1500 real rows)
  int tid = threadIdx.x;
  bool live = (o < 1500);
  if (live) {
    for (int f4 = tid * 4; f4 < 2000; f4 += 2048)
      *(float4*)&row[f4] = *(const float4*)&W[(size_t)o * 2000 + f4];
  }
  __syncthreads();
  int r2 = ((o >> 4) << 5) + (o & 15);
  f16* dh = dst + (size_t)r2 * Kpc;
  f16* dl = dst + (size_t)(r2 + 16) * Kpc;
  for (int j = tid; j < Kpc; j += 512) {
    float w = (live && j < K) ? row[colidx[j]] : 0.f;
    f16 h = (f16)w;
    float hf = (float)h;
    if (__builtin_fabsf(hf) < 6.103515625e-05f) { h = (f16)0.f; hf = 0.f; }
    dh[j] = h;
    dl[j] = (f16)((w - hf) * 4096.0f);
  }
}

// ---------- compact dense spike matrix columns: dst[row][j] = src[row][colidx[j]] ----------
__global__ void gather_cols(const f16* __restrict__ src, f16* __restrict__ dst,
                            const int* __restrict__ colidx, const int* __restrict__ meta,
                            int srcW) {
  int K = meta[0], Kpc = meta[1];
  if (Kpc == 0) return;
  int row = blockIdx.x;  // 4096
  const f16* s = src + (size_t)row * srcW;
  f16* d = dst + (size_t)row * Kpc;
  for (int j = threadIdx.x; j < Kpc; j += 256)
    d[j] = (j < K) ? s[colidx[j]] : (f16)0.f;
}

// ---------- weight prep for layers 2..5 (all interleaved W2) ----------
struct PrepArgs {
  const float* W[4];
  f16* dst[4];
  int Nr[4], Kr[4], Kp[4], Npd[4];
  int boff[5];
};

__global__ void prep_w_all(PrepArgs a) {
  int blk = blockIdx.x;
  int k = 0;
#pragma unroll
  for (int j = 0; j < 3; ++j) k += (blk >= a.boff[j + 1]) ? 1 : 0;
  int i = (blk - a.boff[k]) * 256 + threadIdx.x;
  int Kp = a.Kp[k];
  int kp4 = Kp >> 2;
  int total4 = a.Npd[k] * kp4;
  if (i >= total4) return;
  int o = i / kp4, f = (i - o * kp4) << 2;
  float w[4] = {0.f, 0.f, 0.f, 0.f};
  if (o < a.Nr[k] && f < a.Kr[k]) {
    float4 t = *(const float4*)&a.W[k][(size_t)o * a.Kr[k] + f];
    w[0] = t.x; w[1] = t.y; w[2] = t.z; w[3] = t.w;
  }
  f16x4 h4, l4;
#pragma unroll
  for (int e = 0; e < 4; ++e) {
    f16 h = (f16)w[e];
    float hf = (float)h;
    if (__builtin_fabsf(hf) < 6.103515625e-05f) { h = (f16)0.f; hf = 0.f; }
    h4[e] = h;
    l4[e] = (f16)((w[e] - hf) * 4096.0f);
  }
  int r2 = ((o >> 4) << 5) + (o & 15);
  *(f16x4*)&a.dst[k][(size_t)r2 * Kp + f] = h4;
  *(f16x4*)&a.dst[k][(size_t)(r2 + 16) * Kp + f] = l4;
}

// ---------- fused GEMM + LI_k + LIF_{k+1}, templated on wave-rows ----------
// WM=4: BM=256, 512 thr. WM=2: BM=128, 256 thr. Rows ordered row = b*32 + t.
// grouped: per-16-batch-group K/base (L0). Out != nullptr: fused LI5+max+log_softmax
// epilogue writes final logits. Else: epilogue runs exact li_lif fp32 recurrence via
// per-wave LDS scratch, writes next-layer spikes (f16), optional colFlags aliveness.
template <int WM>
__global__ __launch_bounds__(WM * 128, 4)
void gemm_fused(const f16* __restrict__ A, const f16* __restrict__ B2,
                f16* __restrict__ Spk, float* __restrict__ Out,
                const int* __restrict__ kpcp, int KpFixed, int Np,
                uint* __restrict__ colFlags, int grouped) {
  constexpr int BM = WM * 64;
  constexpr int NT = WM * 128;
  constexpr int BI = 1024 / NT;
  __shared__ f16 smem[BM * 64 + 128 * 64];
  f16* sA = smem;
  f16* sB = smem + BM * 64;
  const int tid = threadIdx.x;
  const int lane = tid & 63;
  const int wave = tid >> 6;
  const int wr = wave >> 1;
  const int wc = wave & 1;

  const int nx = gridDim.x;
  const int flat = blockIdx.y * nx + blockIdx.x;
  const int cpx = (nx * gridDim.y) >> 3;
  const int id = (flat & 7) * cpx + (flat >> 3);
  const int m0 = (id / nx) * BM;
  const int n0 = (id % nx) * 128;

  int Kp;
  size_t aoff, boff;
  if (grouped) {
    int g = m0 >> 9;
    Kp = kpcp[g * 2 + 1];
    aoff = g * ASTR + (size_t)(m0 & 511) * Kp;
    boff = g * BSTR + (size_t)n0 * Kp;
  } else {
    Kp = kpcp ? kpcp[1] : KpFixed;
    aoff = (size_t)m0 * Kp;
    boff = (size_t)n0 * Kp;
  }

  f32x4 zero = {0.f, 0.f, 0.f, 0.f};
  f32x4 acc[4][4];
#pragma unroll
  for (int m = 0; m < 4; ++m)
#pragma unroll
    for (int n = 0; n < 4; ++n) acc[m][n] = zero;

  const f16* Abase = A + aoff;
  const f16* Bbase = B2 + boff;
  const int nkt = Kp >> 6;
  for (int kt = 0; kt < nkt; ++kt) {
    __syncthreads();
    const f16* Ab = Abase + (size_t)kt * 64;
    const f16* Bb = Bbase + (size_t)kt * 64;
#pragma unroll
    for (int j = 0; j < 4; ++j) {  // A: BM*8 chunks = 4*NT
      int q = j * NT + tid;
      int r = q >> 3, c = ((q & 7) ^ (r & 7)) * 8;
      __builtin_amdgcn_global_load_lds((const AS1 void*)(Ab + (size_t)r * Kp + c),
                                       (AS3 void*)(&sA[q * 8]), 16, 0, 0);
    }
#pragma unroll
    for (int j = 0; j < BI; ++j) {  // B: 1024 chunks
      int q = j * NT + tid;
      int r = q >> 3, c = ((q & 7) ^ (r & 7)) * 8;
      __builtin_amdgcn_global_load_lds((const AS1 void*)(Bb + (size_t)r * Kp + c),
                                       (AS3 void*)(&sB[q * 8]), 16, 0, 0);
    }
    __syncthreads();
#pragma unroll
    for (int kk = 0; kk < 2; ++kk) {
      const int lr = lane & 15;
      const int hq = lane >> 4;
      f16x8 af[4], bf[4];
#pragma unroll
      for (int m = 0; m < 4; ++m) {
        int R = wr * 64 + m * 16 + lr;
        int ch = (kk * 4 + hq) ^ (R & 7);
        af[m] = *(const f16x8*)&sA[R * 64 + ch * 8];
      }
#pragma unroll
      for (int n = 0; n < 4; ++n) {
        int R = wc * 64 + n * 16 + lr;
        int ch = (kk * 4 + hq) ^ (R & 7);
        bf[n] = *(const f16x8*)&sB[R * 64 + ch * 8];
      }
#pragma unroll
      for (int m = 0; m < 4; ++m)
#pragma unroll
        for (int n = 0; n < 4; ++n)
          acc[m][n] = __builtin_amdgcn_mfma_f32_16x16x32_f16(af[m], bf[n], acc[m][n], 0, 0, 0);
    }
  }

  const int lr = lane & 15, lq = lane >> 4;
  float* scr = (float*)smem + wave * 1152;  // [64][17] f32 per-wave scratch
  const int baseRow = m0 + wr * 64;

  if (Out) {  // last layer: fused LI5 scan + max + log_softmax (cols 0..9 live in n0==0,wc==0,j==0)
    __syncthreads();
#pragma unroll
    for (int m = 0; m < 4; ++m)
#pragma unroll
      for (int i = 0; i < 4; ++i)
        scr[(m * 16 + lq * 4 + i) * 17 + lr] = acc[m][0][i] + EPS_LO * acc[m][1][i];
    __syncthreads();
    float mx = -3.4e38f;
    if (lane < 32) {
      int bl = lane >> 4, c = lane & 15;
      float vL = 0.f, iL = 0.f;
      for (int t = 0; t < 32; ++t) {
        float g = scr[(bl * 32 + t) * 17 + c];
        float ij = iL + g;
        vL = vL + KM * (ij - vL);
        iL = KS * ij;
        mx = fmaxf(mx, vL);
      }
    }
    float v = (lane < 32 && (lane & 15) < 10) ? mx : -3.4e38f;
    float M = v;
#pragma unroll
    for (int s = 1; s < 16; s <<= 1) M = fmaxf(M, __shfl_xor(M, s));
    float e = (lane < 32 && (lane & 15) < 10) ? expf(v - M) : 0.f;
    float sum = e;
#pragma unroll
    for (int s = 1; s < 16; s <<= 1) sum += __shfl_xor(sum, s);
    if (n0 == 0 && wc == 0 && lane < 32 && (lane & 15) < 10) {
      int b = (baseRow >> 5) + (lane >> 4);
      Out[b * 10 + (lane & 15)] = v - M - logf(sum);
    }
    return;
  }

  // ---- fused LI+LIF epilogue: per wave, 64 rows (= 2 batches x 32 t) x 32 cols ----
  __syncthreads();
#pragma unroll
  for (int h = 0; h < 2; ++h) {
#pragma unroll
    for (int m = 0; m < 4; ++m)
#pragma unroll
      for (int i = 0; i < 4; ++i)
        scr[(m * 16 + lq * 4 + i) * 17 + lr] = acc[m][2 * h][i] + EPS_LO * acc[m][2 * h + 1][i];
    __syncthreads();
    if (lane < 32) {
      int bl = lane >> 4, c = lane & 15;
      float vL = 0.f, iL = 0.f, vF = 0.f, iF = 0.f;
      for (int t = 0; t < 32; ++t) {
        float g = scr[(bl * 32 + t) * 17 + c];
        float ij = iL + g;
        vL = vL + KM * (ij - vL);
        iL = KS * ij;
        float vd = vF + KM * (iF - vF);
        float idec = KS * iF;
        float z = (vd > 1.0f) ? 1.f : 0.f;
        vF = (1.f - z) * vd;
        iF = idec + vL;
        scr[(bl * 32 + t) * 17 + c] = z;
      }
    }
    __syncthreads();
    {
      int row = lane;
      f16x8 v0, v1;
#pragma unroll
      for (int cc = 0; cc < 8; ++cc) {
        v0[cc] = (f16)scr[row * 17 + cc];
        v1[cc] = (f16)scr[row * 17 + 8 + cc];
      }
      size_t go = (size_t)(baseRow + row) * Np + (n0 >> 1) + wc * 32 + h * 16;
      *(f16x8*)&Spk[go] = v0;
      *(f16x8*)&Spk[go + 8] = v1;
      if (colFlags) {  // column spike-aliveness for next-layer K compaction
        uint bits = 0u;
#pragma unroll
        for (int cc = 0; cc < 8; ++cc) {
          bits |= (__any((float)v0[cc] != 0.f) ? 1u : 0u) << cc;
          bits |= (__any((float)v1[cc] != 0.f) ? 1u : 0u) << (8 + cc);
        }
        int cstart = (n0 >> 1) + wc * 32 + h * 16;  // multiple of 16
        if (lane == 0 && bits) atomicOr(&colFlags[cstart >> 5], bits << (cstart & 31));
      }
    }
    __syncthreads();
  }
}

extern "C" void kernel_launch(void* const* d_in, const int* in_sizes, int n_in,
                              void* d_out, int out_size, void* d_ws, size_t ws_size,
                              hipStream_t stream) {
  const float* img = (const float*)d_in[0];
  static const int Nr[6]  = {2000, 1500, 1000, 500, 100, 10};
  static const int Kr[6]  = {12000, 2000, 1500, 1000, 500, 100};
  static const int Npd[6] = {2048, 1536, 1024, 512, 128, 128};
  static const int Kpd[6] = {12032, 2048, 1536, 1024, 512, 128};

  char* p = (char*)d_ws;
  f16* W0g = (f16*)p; p += 8 * BSTR * 2;             // per-group interleaved W0 (160 MB)
  f16* wa[6];
  wa[0] = W0g;
  for (int k = 1; k < 6; ++k) {
    wa[k] = (f16*)p; p += (size_t)2 * Npd[k] * Kpd[k] * 2;
  }
  f16* Ag = (f16*)p;   p += 8 * ASTR * 2;            // per-group compacted L0 A (21 MB)
  f16* T0 = (f16*)p;   p += (size_t)4096 * 2048 * 2; // spike ping
  f16* T1 = (f16*)p;   p += (size_t)4096 * 2048 * 2; // spike pong
  uint* Z = (uint*)p;  p += (size_t)128 * 12032 * 4; // spike bitmasks
  uint* flags = (uint*)p;  p += 8 * 376 * 4;         // per-group L0 column flags
  uint* flags1 = (uint*)p; p += 64 * 4;              // L1-input column flags
  int* colidx = (int*)p;  p += 8 * 12032 * 4;
  int* colidx1 = (int*)p; p += 2048 * 4;
  int* meta = (int*)p;  p += 16 * 4;
  int* meta1 = (int*)p; p += 2 * 4;

  // --- layer-0 per-group column compaction chain ---
  hipMemsetAsync(flags, 0, (8 * 376 + 64) * 4, stream);  // flags + flags1 (adjacent)
  enc_flags<<<(128 * 3000 + 255) / 256, 256, 0, stream>>>(img, Z, flags);
  scan_cols<<<8, 512, 0, stream>>>(flags, colidx, meta, 376, 12032, KCAP0);
  spike_gather<<<dim3(80, 8), 256, 0, stream>>>(Z, Ag, colidx, meta);
  prep_w0_row<<<2048, 512, 0, stream>>>((const float*)d_in[1], W0g, colidx, meta);

  // --- layers 2..5 weight prep ---
  PrepArgs pa;
  int nb = 0;
  for (int k = 2; k < 6; ++k) {
    int kk = k - 2;
    pa.W[kk] = (const float*)d_in[k + 1];
    pa.dst[kk] = wa[k];
    pa.Nr[kk] = Nr[k]; pa.Kr[kk] = Kr[k]; pa.Kp[kk] = Kpd[k]; pa.Npd[kk] = Npd[k];
    pa.boff[kk] = nb;
    nb += ((Npd[k] * Kpd[k]) >> 2) / 256;
  }
  pa.boff[4] = nb;
  prep_w_all<<<nb, 256, 0, stream>>>(pa);

  // --- L0: per-group-K GEMM + LI0/LIF1 epilogue + column-aliveness flags ---
  gemm_fused<4><<<dim3(32, 16), dim3(512), 0, stream>>>(
      Ag, W0g, T0, nullptr, meta, 0, Npd[0], flags1, 1);

  // --- L1 K-compaction: scan -> gather spikes -> prep W1 at alive columns ---
  scan_cols<<<1, 512, 0, stream>>>(flags1, colidx1, meta1, 64, 2048, 2048);
  gather_cols<<<4096, 256, 0, stream>>>(T0, T1, colidx1, meta1, Npd[0]);
  prep_w1_row<<<1536, 512, 0, stream>>>((const float*)d_in[2], wa[1], colidx1, meta1);

  // --- L1 (runtime K) then L2..L5 (L5 fuses final softmax); spikes alternate T0/T1 ---
  gemm_fused<4><<<dim3(2 * Npd[1] / 128, 16), dim3(512), 0, stream>>>(
      T1, wa[1], T0, nullptr, meta1, 0, Npd[1], nullptr, 0);
  gemm_fused<2><<<dim3(2 * Npd[2] / 128, 32), dim3(256), 0, stream>>>(
      T0, wa[2], T1, nullptr, nullptr, Kpd[2], Npd[2], nullptr, 0);
  gemm_fused<2><<<dim3(2 * Npd[3] / 128, 32), dim3(256), 0, stream>>>(
      T1, wa[3], T0, nullptr, nullptr, Kpd[3], Npd[3], nullptr, 0);
  gemm_fused<2><<<dim3(2 * Npd[4] / 128, 32), dim3(256), 0, stream>>>(
      T0, wa[4], T1, nullptr, nullptr, Kpd[4], Npd[4], nullptr, 0);
  gemm_fused<2><<<dim3(2 * Npd[5] / 128, 32), dim3(256), 0, stream>>>(
      T1, wa[5], nullptr, (float*)d_out, nullptr, Kpd[5], Npd[5], nullptr, 0);
}